// Round 1
// baseline (596.811 us; speedup 1.0000x reference)
//
#include <hip/hip_runtime.h>

// LiftSplat voxel pooling: scatter-add x[NPRIME, 256] into BEV [4, 256, 400, 200]
// Strategy: bucket-CSR (b, x, ytile) -> output-driven gather, LDS-tiled transpose.
//
// ws layout (int32 elements):
//   counts  [0, 6400)
//   cursors [6400, 12800)
//   starts  [12800, 19201)     (6401 entries)
//   bin     [19456, 19456+NPRIME)   packed (p<<6)|y_local
// total = (19456 + 173184) * 4 B = 770,560 B

#define NPRIME   173184
#define NCH      256
#define NBATCH   4
#define GNX      400
#define GNY      200
#define NBUCKETS 6400   // NBATCH * GNX * ceil(GNY/64)

__global__ void k_zero_counts(int* __restrict__ counts) {
    int i = blockIdx.x * blockDim.x + threadIdx.x;
    if (i < NBUCKETS) counts[i] = 0;
}

__global__ void k_hist(const int4* __restrict__ geom, int* __restrict__ counts) {
    int p = blockIdx.x * blockDim.x + threadIdx.x;
    if (p >= NPRIME) return;
    int4 g = geom[p];                       // x=gx, y=gy, z=gz(=0), w=gb
    int bucket = ((g.w * GNX + g.x) << 2) | (g.y >> 6);
    atomicAdd(&counts[bucket], 1);
}

__global__ void k_scan(const int* __restrict__ counts,
                       int* __restrict__ starts, int* __restrict__ cursors) {
    __shared__ int sums[256];
    int tid = threadIdx.x;
    int local[25];
    int s = 0;
    #pragma unroll
    for (int j = 0; j < 25; ++j) { local[j] = counts[tid * 25 + j]; s += local[j]; }
    sums[tid] = s;
    __syncthreads();
    // Hillis-Steele inclusive scan
    for (int off = 1; off < 256; off <<= 1) {
        int v = (tid >= off) ? sums[tid - off] : 0;
        __syncthreads();
        sums[tid] += v;
        __syncthreads();
    }
    int run = (tid == 0) ? 0 : sums[tid - 1];   // exclusive offset
    #pragma unroll
    for (int j = 0; j < 25; ++j) {
        int idx = tid * 25 + j;
        starts[idx] = run;
        cursors[idx] = run;
        run += local[j];
    }
    if (tid == 255) starts[NBUCKETS] = run;     // == NPRIME
}

__global__ void k_fill(const int4* __restrict__ geom,
                       int* __restrict__ cursors, int* __restrict__ bin) {
    int p = blockIdx.x * blockDim.x + threadIdx.x;
    if (p >= NPRIME) return;
    int4 g = geom[p];
    int bucket = ((g.w * GNX + g.x) << 2) | (g.y >> 6);
    int pos = atomicAdd(&cursors[bucket], 1);
    bin[pos] = (p << 6) | (g.y & 63);
}

// One block per bucket: 64 y-slots x 256 channels accumulated in LDS (64 KB),
// XOR-swizzled so both the accumulate (channel-owned, no atomics) and the
// transposed write-out are bank-conflict-free.
__device__ __forceinline__ int lds_loc(int y, int c) {
    return y * 256 + (c ^ (y & 31));
}

__global__ __launch_bounds__(256) void k_gather(
        const float* __restrict__ xin,
        const int* __restrict__ starts, const int* __restrict__ bin,
        float* __restrict__ out) {
    extern __shared__ float lds[];   // 64*256 floats = 64 KB
    int tid = threadIdx.x;           // = channel in accumulate phase
    int bucket = blockIdx.x;
    int ytile = bucket & 3;
    int bx = bucket >> 2;
    int xi = bx % GNX;
    int b  = bx / GNX;
    int y0 = ytile << 6;

    // zero my channel's column across all 64 y rows (single-owner, no sync needed
    // before accumulate since only this thread touches these addresses)
    #pragma unroll
    for (int yl = 0; yl < 64; ++yl) lds[lds_loc(yl, tid)] = 0.0f;

    int s = starts[bucket];
    int e = starts[bucket + 1];
    int i = s;
    for (; i + 4 <= e; i += 4) {
        int pk0 = bin[i + 0];
        int pk1 = bin[i + 1];
        int pk2 = bin[i + 2];
        int pk3 = bin[i + 3];
        float v0 = xin[(pk0 >> 6) * NCH + tid];
        float v1 = xin[(pk1 >> 6) * NCH + tid];
        float v2 = xin[(pk2 >> 6) * NCH + tid];
        float v3 = xin[(pk3 >> 6) * NCH + tid];
        // same-thread RMW even if y repeats -> program order keeps it correct
        lds[lds_loc(pk0 & 63, tid)] += v0;
        lds[lds_loc(pk1 & 63, tid)] += v1;
        lds[lds_loc(pk2 & 63, tid)] += v2;
        lds[lds_loc(pk3 & 63, tid)] += v3;
    }
    for (; i < e; ++i) {
        int pk = bin[i];
        lds[lds_loc(pk & 63, tid)] += xin[(pk >> 6) * NCH + tid];
    }
    __syncthreads();

    // write phase: out[b][c][x][y], float4 along y (coalesced per wave)
    int nvalid = GNY - y0;              // 64,64,64,8
    if (nvalid > 64) nvalid = 64;
    int col4  = tid & 15;               // y-quad within tile
    int rbase = tid >> 4;               // channel sub-index
    if (col4 * 4 < nvalid) {
        #pragma unroll
        for (int ii = 0; ii < 16; ++ii) {
            int c = ii * 16 + rbase;
            int y = col4 * 4;
            float4 v;
            v.x = lds[lds_loc(y + 0, c)];
            v.y = lds[lds_loc(y + 1, c)];
            v.z = lds[lds_loc(y + 2, c)];
            v.w = lds[lds_loc(y + 3, c)];
            int o = ((b * NCH + c) * GNX + xi) * GNY + y0 + y;
            *reinterpret_cast<float4*>(&out[o]) = v;
        }
    }
}

extern "C" void kernel_launch(void* const* d_in, const int* in_sizes, int n_in,
                              void* d_out, int out_size, void* d_ws, size_t ws_size,
                              hipStream_t stream) {
    const float* x    = (const float*)d_in[0];
    const int4*  geom = (const int4*)d_in[1];
    float* out = (float*)d_out;

    int* w       = (int*)d_ws;
    int* counts  = w;
    int* cursors = w + 6400;
    int* starts  = w + 12800;
    int* bin     = w + 19456;

    const int PT_BLOCKS = (NPRIME + 255) / 256;   // 677

    k_zero_counts<<<(NBUCKETS + 255) / 256, 256, 0, stream>>>(counts);
    k_hist<<<PT_BLOCKS, 256, 0, stream>>>(geom, counts);
    k_scan<<<1, 256, 0, stream>>>(counts, starts, cursors);
    k_fill<<<PT_BLOCKS, 256, 0, stream>>>(geom, cursors, bin);
    k_gather<<<NBUCKETS, 256, 64 * 256 * sizeof(float), stream>>>(x, starts, bin, out);
}